// Round 4
// baseline (3234.838 us; speedup 1.0000x reference)
//
#include <hip/hip_runtime.h>
#include <hip/hip_bf16.h>

// B=8192, T=32, D_IN=2, EMB=128, H=256, 4H=1024
// 128 blocks x 1024 threads (16 waves); block owns 64 batch rows.
// Wave wid owns (w=wid>>2, s=wid&3): cols q*256 + w*64 + s*16 + [0,16), q=0..3 gates.
// MFMA 16x16x32 bf16 swapped operands: D = z^T tile, batch row in lane&15; 4 row-tiles.
// Grid-wide per-timestep alignment barrier (perf-only; blocks are independent)
// keeps all blocks walking the shared 1.75MB weight set simultaneously -> L2-resident.

typedef __attribute__((ext_vector_type(8))) __bf16 bf16x8;
typedef __attribute__((ext_vector_type(4))) __bf16 bf16x4;
typedef __attribute__((ext_vector_type(4))) float f32x4;

#define MFMA16(a, b, c) __builtin_amdgcn_mfma_f32_16x16x32_bf16(a, b, c, 0, 0, 0)

__device__ __forceinline__ float fexp2(float x) {
#if __has_builtin(__builtin_amdgcn_exp2f)
  return __builtin_amdgcn_exp2f(x);
#else
  return exp2f(x);
#endif
}
__device__ __forceinline__ float frcp(float x) {
#if __has_builtin(__builtin_amdgcn_rcpf)
  return __builtin_amdgcn_rcpf(x);
#else
  return 1.0f / x;
#endif
}
__device__ __forceinline__ float fsig(float x) {
  return frcp(1.0f + fexp2(-1.44269504f * x));
}
__device__ __forceinline__ float ftanh(float x) {
  return 1.0f - 2.0f * frcp(1.0f + fexp2(2.88539008f * x));
}

// ---- weight prep: swizzle [W;U] (K x 1024) fp32 -> per-frag bf16 order ----
__global__ void prep_w0(const float* __restrict__ W0, const float* __restrict__ U0,
                        __bf16* __restrict__ o) {
  const int f = blockIdx.x * 256 + threadIdx.x;  // < 393216
  const int j = f & 7, l5 = (f >> 3) & 63, g = f >> 9;
  const int kc = g % 12, q = (g / 12) & 3, wid = g / 48;
  const int k = (kc << 5) + ((l5 >> 4) << 3) + j;
  const int c = (q << 8) + ((wid >> 2) << 6) + ((wid & 3) << 4) + (l5 & 15);
  const float v = (k < 128) ? W0[(k << 10) + c] : U0[((k - 128) << 10) + c];
  o[f] = (__bf16)v;
}
__global__ void prep_w1(const float* __restrict__ W1, const float* __restrict__ U1,
                        __bf16* __restrict__ o) {
  const int f = blockIdx.x * 256 + threadIdx.x;  // < 524288
  const int j = f & 7, l5 = (f >> 3) & 63, g = f >> 9;
  const int kcx = g & 15, q = (g >> 4) & 3, wid = g >> 6;
  const int k = (kcx << 5) + ((l5 >> 4) << 3) + j;
  const int c = (q << 8) + ((wid >> 2) << 6) + ((wid & 3) << 4) + (l5 & 15);
  const float v = (k < 256) ? W1[(k << 10) + c] : U1[((k - 256) << 10) + c];
  o[f] = (__bf16)v;
}

__global__ __launch_bounds__(1024)
void lstm_fused(const float* __restrict__ traj,
                const float* __restrict__ Wemb,
                const float* __restrict__ bemb,
                const float* __restrict__ bias0,
                const float* __restrict__ bias1,
                const __bf16* __restrict__ wb0,
                const __bf16* __restrict__ wb1,
                float* __restrict__ out,
                unsigned int* flags) {
  __shared__ float s_We[384];        // We[0][:], We[1][:], be[:]
  __shared__ float s_b[2][1024];     // bias in (ct, cc) order
  __shared__ float s_traj[4096];     // [t][r][d]: t*128 + r*2 + d
  __shared__ __bf16 s_h0[2][16384];  // [buf][r*256 + (e ^ ((r&7)<<3))]
  __shared__ __bf16 s_h1[2][16384];

  const int tid = threadIdx.x;
  const int wid = tid >> 6;
  const int l = tid & 63;
  const int lr = l & 15, lg = l >> 4;
  const int w = wid >> 2, s4 = wid & 3;
  const int xr = (lr & 7) << 3;  // bf16-elem swizzle, fn of row only
  const int r0 = blockIdx.x << 6;

  if (tid < 384) s_We[tid] = (tid < 256) ? Wemb[tid] : bemb[tid - 256];
  {
    const int ct = tid >> 4, cc = tid & 15;
    const int wd = ct >> 2, q = ct & 3;
    const int col = (q << 8) + ((wd >> 2) << 6) + ((wd & 3) << 4) + cc;
    s_b[0][tid] = bias0[col];
    s_b[1][tid] = bias1[col];
  }
  for (int i = tid; i < 4096; i += 1024) {
    const int r = i >> 6, tt = (i >> 1) & 31, d = i & 1;
    s_traj[(tt << 7) + (r << 1) + d] = traj[(r0 << 6) + i];
  }
  for (int i = tid; i < 16384; i += 1024) {
    s_h0[0][i] = (__bf16)0.f;
    s_h1[0][i] = (__bf16)0.f;
  }
  __syncthreads();

  float c0s[4][4] = {};
  float c1s[4][4] = {};
  const __bf16* wp0 = wb0 + wid * 48 * 512 + l * 8;
  const __bf16* wp1 = wb1 + wid * 64 * 512 + l * 8;
  const int e0 = (w << 6) + (s4 << 4) + (lg << 2);

#pragma unroll 1
  for (int t = 0; t < 32; ++t) {
    const int cur = t & 1, nxt = cur ^ 1;

    {  // ---------------- layer 0: z = [x_t | h0] @ [W0;U0] + b0 ----------------
      f32x4 acc[4][4];  // [q][rt]
#pragma unroll
      for (int q = 0; q < 4; ++q) {
        const f32x4 b = *reinterpret_cast<const f32x4*>(
            &s_b[0][(((wid << 2) + q) << 4) + (lg << 2)]);
#pragma unroll
        for (int rt = 0; rt < 4; ++rt) acc[q][rt] = b;
      }
      float t0v[4], t1v[4];
#pragma unroll
      for (int rt = 0; rt < 4; ++rt) {
        const int r = (rt << 4) + lr;
        t0v[rt] = s_traj[(t << 7) + (r << 1)];
        t1v[rt] = s_traj[(t << 7) + (r << 1) + 1];
      }
#pragma unroll
      for (int kc = 0; kc < 4; ++kc) {  // x-part computed on the fly
        bf16x8 ia[4];
#pragma unroll
        for (int rt = 0; rt < 4; ++rt) {
#pragma unroll
          for (int j = 0; j < 8; ++j) {
            const int k = (kc << 5) + (lg << 3) + j;
            const float x =
                fmaf(t0v[rt], s_We[k], fmaf(t1v[rt], s_We[128 + k], s_We[256 + k]));
            ia[rt][j] = (__bf16)fmaxf(x, 0.f);
          }
        }
#pragma unroll
        for (int q = 0; q < 4; ++q) {
          const bf16x8 wf = *reinterpret_cast<const bf16x8*>(wp0 + (q * 12 + kc) * 512);
#pragma unroll
          for (int rt = 0; rt < 4; ++rt) acc[q][rt] = MFMA16(wf, ia[rt], acc[q][rt]);
        }
      }
#pragma unroll
      for (int kc = 0; kc < 8; ++kc) {  // h0 part from LDS
        bf16x8 ia[4];
#pragma unroll
        for (int rt = 0; rt < 4; ++rt) {
          const int r = (rt << 4) + lr;
          const int idx = (r << 8) + (((kc << 5) + (lg << 3)) ^ xr);
          ia[rt] = *reinterpret_cast<const bf16x8*>(&s_h0[cur][idx]);
        }
#pragma unroll
        for (int q = 0; q < 4; ++q) {
          const bf16x8 wf =
              *reinterpret_cast<const bf16x8*>(wp0 + (q * 12 + 4 + kc) * 512);
#pragma unroll
          for (int rt = 0; rt < 4; ++rt) acc[q][rt] = MFMA16(wf, ia[rt], acc[q][rt]);
        }
      }
#pragma unroll
      for (int rt = 0; rt < 4; ++rt) {
        const int r = (rt << 4) + lr;
        bf16x4 hv;
        f32x4 hfv, cfv;
#pragma unroll
        for (int i = 0; i < 4; ++i) {
          const float cc = fsig(acc[1][rt][i]) * c0s[rt][i] +
                           fsig(acc[0][rt][i]) * ftanh(acc[2][rt][i]);
          c0s[rt][i] = cc;
          const float hh = fsig(acc[3][rt][i]) * ftanh(cc);
          hv[i] = (__bf16)hh;
          hfv[i] = hh;
          cfv[i] = cc;
        }
        *reinterpret_cast<bf16x4*>(&s_h0[nxt][(r << 8) + (e0 ^ xr)]) = hv;
        if (t == 31) {
          const int base = ((r0 + r) << 8) + e0;
          *reinterpret_cast<f32x4*>(out + 67108864 + base) = hfv;  // h0 final
          *reinterpret_cast<f32x4*>(out + 69206016 + base) = cfv;  // c0 final
        }
      }
    }
    __syncthreads();

    {  // ---------------- layer 1: z = [h0_new | h1] @ [W1;U1] + b1 ----------------
      f32x4 acc[4][4];
#pragma unroll
      for (int q = 0; q < 4; ++q) {
        const f32x4 b = *reinterpret_cast<const f32x4*>(
            &s_b[1][(((wid << 2) + q) << 4) + (lg << 2)]);
#pragma unroll
        for (int rt = 0; rt < 4; ++rt) acc[q][rt] = b;
      }
#pragma unroll
      for (int hf2 = 0; hf2 < 2; ++hf2) {
        const __bf16* src = hf2 ? s_h1[cur] : s_h0[nxt];
#pragma unroll
        for (int kc = 0; kc < 8; ++kc) {
          bf16x8 ib[4];
#pragma unroll
          for (int rt = 0; rt < 4; ++rt) {
            const int r = (rt << 4) + lr;
            const int idx = (r << 8) + (((kc << 5) + (lg << 3)) ^ xr);
            ib[rt] = *reinterpret_cast<const bf16x8*>(&src[idx]);
          }
#pragma unroll
          for (int q = 0; q < 4; ++q) {
            const bf16x8 wf = *reinterpret_cast<const bf16x8*>(
                wp1 + (q * 16 + hf2 * 8 + kc) * 512);
#pragma unroll
            for (int rt = 0; rt < 4; ++rt) acc[q][rt] = MFMA16(wf, ib[rt], acc[q][rt]);
          }
        }
      }
#pragma unroll
      for (int rt = 0; rt < 4; ++rt) {
        const int r = (rt << 4) + lr;
        bf16x4 hv;
        f32x4 cfv;
#pragma unroll
        for (int i = 0; i < 4; ++i) {
          const float cc = fsig(acc[1][rt][i]) * c1s[rt][i] +
                           fsig(acc[0][rt][i]) * ftanh(acc[2][rt][i]);
          c1s[rt][i] = cc;
          const float hh = fsig(acc[3][rt][i]) * ftanh(cc);
          hv[i] = (__bf16)hh;
          cfv[i] = cc;
        }
        *reinterpret_cast<bf16x4*>(&s_h1[nxt][(r << 8) + (e0 ^ xr)]) = hv;
        if (t == 31) {
          const int base = ((r0 + r) << 8) + e0;
          *reinterpret_cast<f32x4*>(out + 73400320 + base) = cfv;  // c1 final
        }
      }
    }
    __syncthreads();

    {  // ---- coalesced y write: each lane owns a full 64B line segment ----
      const int row = tid >> 4, cl = tid & 15;
      const int xw = (row & 7) << 3;
      const __bf16* hp = &s_h1[nxt][row << 8];
      const bf16x8 a = *reinterpret_cast<const bf16x8*>(&hp[(cl << 4) ^ xw]);
      const bf16x8 b = *reinterpret_cast<const bf16x8*>(&hp[((cl << 4) + 8) ^ xw]);
      f32x4 v0, v1, v2, v3;
#pragma unroll
      for (int i = 0; i < 4; ++i) {
        v0[i] = (float)a[i];
        v1[i] = (float)a[4 + i];
        v2[i] = (float)b[i];
        v3[i] = (float)b[4 + i];
      }
      float* gp = out + ((((r0 + row) << 5) + t) << 8) + (cl << 4);
      *reinterpret_cast<f32x4*>(gp) = v0;
      *reinterpret_cast<f32x4*>(gp + 4) = v1;
      *reinterpret_cast<f32x4*>(gp + 8) = v2;
      *reinterpret_cast<f32x4*>(gp + 12) = v3;
      if (t == 31) {  // h1 final = y1[:, 31, :]
        float* fp = out + 71303168 + ((r0 + row) << 8) + (cl << 4);
        *reinterpret_cast<f32x4*>(fp) = v0;
        *reinterpret_cast<f32x4*>(fp + 4) = v1;
        *reinterpret_cast<f32x4*>(fp + 8) = v2;
        *reinterpret_cast<f32x4*>(fp + 12) = v3;
      }
    }

    // ---- grid alignment barrier (perf-only: blocks are data-independent) ----
    if (flags != nullptr && t < 31) {
      __syncthreads();
      if (tid == 0) {
        __hip_atomic_store(&flags[(t << 7) + blockIdx.x], 1u, __ATOMIC_RELAXED,
                           __HIP_MEMORY_SCOPE_AGENT);
      }
      if (tid < 128) {
        while (__hip_atomic_load(&flags[(t << 7) + tid], __ATOMIC_RELAXED,
                                 __HIP_MEMORY_SCOPE_AGENT) == 0u) {
          __builtin_amdgcn_s_sleep(8);
        }
      }
      __syncthreads();
    }
  }
}

extern "C" void kernel_launch(void* const* d_in, const int* in_sizes, int n_in,
                              void* d_out, int out_size, void* d_ws, size_t ws_size,
                              hipStream_t stream) {
  const float* traj = (const float*)d_in[0];
  const float* Wemb = (const float*)d_in[1];
  const float* bemb = (const float*)d_in[2];
  const float* W0 = (const float*)d_in[3];
  const float* U0 = (const float*)d_in[4];
  const float* b0 = (const float*)d_in[5];
  const float* W1 = (const float*)d_in[6];
  const float* U1 = (const float*)d_in[7];
  const float* b1 = (const float*)d_in[8];
  float* out = (float*)d_out;

  __bf16* wb0 = (__bf16*)d_ws;  // 393216 elems = 768 KB
  __bf16* wb1 = wb0 + 393216;   // 524288 elems = 1 MB
  const size_t flags_off = 1835008;       // bytes; 256KB-aligned
  const size_t flags_bytes = 32 * 128 * sizeof(unsigned int);  // 16 KB
  unsigned int* flags = nullptr;
  if (ws_size >= flags_off + flags_bytes) {
    flags = (unsigned int*)((char*)d_ws + flags_off);
    hipMemsetAsync(flags, 0, flags_bytes, stream);
  }

  hipLaunchKernelGGL(prep_w0, dim3(1536), dim3(256), 0, stream, W0, U0, wb0);
  hipLaunchKernelGGL(prep_w1, dim3(2048), dim3(256), 0, stream, W1, U1, wb1);
  hipLaunchKernelGGL(lstm_fused, dim3(128), dim3(1024), 0, stream,
                     traj, Wemb, bemb, b0, b1, wb0, wb1, out, flags);
}

// Round 5
// 2886.276 us; speedup vs baseline: 1.1208x; 1.1208x over previous
//
#include <hip/hip_runtime.h>
#include <hip/hip_bf16.h>

// B=8192, T=32, D_IN=2, EMB=128, H=256, 4H=1024
// 128 blocks x 1024 threads (16 waves); block owns 64 batch rows.
// Wave wid owns (w=wid>>2, s=wid&3): cols q*256 + w*64 + s*16 + [0,16), q=0..3 gates.
// MFMA 16x16x32 bf16 swapped operands: D = z^T tile, batch row in lane&15; 4 row-tiles.
// All bulk global stores are full-cacheline (64 lanes x 16B contiguous per
// instruction) to avoid TCC partial-line write-allocate fetches (r4 lesson).

typedef __attribute__((ext_vector_type(8))) __bf16 bf16x8;
typedef __attribute__((ext_vector_type(4))) __bf16 bf16x4;
typedef __attribute__((ext_vector_type(4))) float f32x4;

#define MFMA16(a, b, c) __builtin_amdgcn_mfma_f32_16x16x32_bf16(a, b, c, 0, 0, 0)

__device__ __forceinline__ float fexp2(float x) {
#if __has_builtin(__builtin_amdgcn_exp2f)
  return __builtin_amdgcn_exp2f(x);
#else
  return exp2f(x);
#endif
}
__device__ __forceinline__ float frcp(float x) {
#if __has_builtin(__builtin_amdgcn_rcpf)
  return __builtin_amdgcn_rcpf(x);
#else
  return 1.0f / x;
#endif
}
__device__ __forceinline__ float fsig(float x) {
  return frcp(1.0f + fexp2(-1.44269504f * x));
}
__device__ __forceinline__ float ftanh(float x) {
  return 1.0f - 2.0f * frcp(1.0f + fexp2(2.88539008f * x));
}

// ---- weight prep: swizzle [W;U] (K x 1024) fp32 -> per-frag bf16 order ----
__global__ void prep_w0(const float* __restrict__ W0, const float* __restrict__ U0,
                        __bf16* __restrict__ o) {
  const int f = blockIdx.x * 256 + threadIdx.x;  // < 393216
  const int j = f & 7, l5 = (f >> 3) & 63, g = f >> 9;
  const int kc = g % 12, q = (g / 12) & 3, wid = g / 48;
  const int k = (kc << 5) + ((l5 >> 4) << 3) + j;
  const int c = (q << 8) + ((wid >> 2) << 6) + ((wid & 3) << 4) + (l5 & 15);
  const float v = (k < 128) ? W0[(k << 10) + c] : U0[((k - 128) << 10) + c];
  o[f] = (__bf16)v;
}
__global__ void prep_w1(const float* __restrict__ W1, const float* __restrict__ U1,
                        __bf16* __restrict__ o) {
  const int f = blockIdx.x * 256 + threadIdx.x;  // < 524288
  const int j = f & 7, l5 = (f >> 3) & 63, g = f >> 9;
  const int kcx = g & 15, q = (g >> 4) & 3, wid = g >> 6;
  const int k = (kcx << 5) + ((l5 >> 4) << 3) + j;
  const int c = (q << 8) + ((wid >> 2) << 6) + ((wid & 3) << 4) + (l5 & 15);
  const float v = (k < 256) ? W1[(k << 10) + c] : U1[((k - 256) << 10) + c];
  o[f] = (__bf16)v;
}

__global__ __launch_bounds__(1024)
void lstm_fused(const float* __restrict__ traj,
                const float* __restrict__ Wemb,
                const float* __restrict__ bemb,
                const float* __restrict__ bias0,
                const float* __restrict__ bias1,
                const __bf16* __restrict__ wb0,
                const __bf16* __restrict__ wb1,
                float* __restrict__ out) {
  __shared__ float s_We[384];        // We[0][:], We[1][:], be[:]
  __shared__ float s_b[2][1024];     // bias in (ct, cc) order
  __shared__ float s_traj[4096];     // [t][r][d]: t*128 + r*2 + d
  __shared__ __bf16 s_h0[2][16384];  // [buf][r*256 + (e ^ ((r&7)<<3))]
  __shared__ __bf16 s_h1[2][16384];

  const int tid = threadIdx.x;
  const int wid = tid >> 6;
  const int l = tid & 63;
  const int lr = l & 15, lg = l >> 4;
  const int w = wid >> 2, s4 = wid & 3;
  const int xr = (lr & 7) << 3;  // bf16-elem swizzle, fn of row only
  const int r0 = blockIdx.x << 6;

  if (tid < 384) s_We[tid] = (tid < 256) ? Wemb[tid] : bemb[tid - 256];
  {
    const int ct = tid >> 4, cc = tid & 15;
    const int wd = ct >> 2, q = ct & 3;
    const int col = (q << 8) + ((wd >> 2) << 6) + ((wd & 3) << 4) + cc;
    s_b[0][tid] = bias0[col];
    s_b[1][tid] = bias1[col];
  }
  for (int i = tid; i < 4096; i += 1024) {
    const int r = i >> 6, tt = (i >> 1) & 31, d = i & 1;
    s_traj[(tt << 7) + (r << 1) + d] = traj[(r0 << 6) + i];
  }
  for (int i = tid; i < 16384; i += 1024) {
    s_h0[0][i] = (__bf16)0.f;
    s_h1[0][i] = (__bf16)0.f;
  }
  __syncthreads();

  float c0s[4][4] = {};
  float c1s[4][4] = {};
  const __bf16* wp0 = wb0 + wid * 48 * 512 + l * 8;
  const __bf16* wp1 = wb1 + wid * 64 * 512 + l * 8;
  const int e0 = (w << 6) + (s4 << 4) + (lg << 2);

#pragma unroll 1
  for (int t = 0; t < 32; ++t) {
    const int cur = t & 1, nxt = cur ^ 1;

    {  // ---------------- layer 0: z = [x_t | h0] @ [W0;U0] + b0 ----------------
      f32x4 acc[4][4];  // [q][rt]
#pragma unroll
      for (int q = 0; q < 4; ++q) {
        const f32x4 b = *reinterpret_cast<const f32x4*>(
            &s_b[0][(((wid << 2) + q) << 4) + (lg << 2)]);
#pragma unroll
        for (int rt = 0; rt < 4; ++rt) acc[q][rt] = b;
      }
      float t0v[4], t1v[4];
#pragma unroll
      for (int rt = 0; rt < 4; ++rt) {
        const int r = (rt << 4) + lr;
        t0v[rt] = s_traj[(t << 7) + (r << 1)];
        t1v[rt] = s_traj[(t << 7) + (r << 1) + 1];
      }
#pragma unroll
      for (int kc = 0; kc < 4; ++kc) {  // x-part computed on the fly
        bf16x8 ia[4];
#pragma unroll
        for (int rt = 0; rt < 4; ++rt) {
#pragma unroll
          for (int j = 0; j < 8; ++j) {
            const int k = (kc << 5) + (lg << 3) + j;
            const float x =
                fmaf(t0v[rt], s_We[k], fmaf(t1v[rt], s_We[128 + k], s_We[256 + k]));
            ia[rt][j] = (__bf16)fmaxf(x, 0.f);
          }
        }
#pragma unroll
        for (int q = 0; q < 4; ++q) {
          const bf16x8 wf = *reinterpret_cast<const bf16x8*>(wp0 + (q * 12 + kc) * 512);
#pragma unroll
          for (int rt = 0; rt < 4; ++rt) acc[q][rt] = MFMA16(wf, ia[rt], acc[q][rt]);
        }
      }
#pragma unroll
      for (int kc = 0; kc < 8; ++kc) {  // h0 part from LDS
        bf16x8 ia[4];
#pragma unroll
        for (int rt = 0; rt < 4; ++rt) {
          const int r = (rt << 4) + lr;
          const int idx = (r << 8) + (((kc << 5) + (lg << 3)) ^ xr);
          ia[rt] = *reinterpret_cast<const bf16x8*>(&s_h0[cur][idx]);
        }
#pragma unroll
        for (int q = 0; q < 4; ++q) {
          const bf16x8 wf =
              *reinterpret_cast<const bf16x8*>(wp0 + (q * 12 + 4 + kc) * 512);
#pragma unroll
          for (int rt = 0; rt < 4; ++rt) acc[q][rt] = MFMA16(wf, ia[rt], acc[q][rt]);
        }
      }
#pragma unroll
      for (int rt = 0; rt < 4; ++rt) {
        const int r = (rt << 4) + lr;
        bf16x4 hv;
        f32x4 cfv;
#pragma unroll
        for (int i = 0; i < 4; ++i) {
          const float cc = fsig(acc[1][rt][i]) * c0s[rt][i] +
                           fsig(acc[0][rt][i]) * ftanh(acc[2][rt][i]);
          c0s[rt][i] = cc;
          const float hh = fsig(acc[3][rt][i]) * ftanh(cc);
          hv[i] = (__bf16)hh;
          cfv[i] = cc;
        }
        *reinterpret_cast<bf16x4*>(&s_h0[nxt][(r << 8) + (e0 ^ xr)]) = hv;
        if (t == 31) {  // c0 final (fp32 accuracy required; small scatter)
          *reinterpret_cast<f32x4*>(out + 69206016 + ((r0 + r) << 8) + e0) = cfv;
        }
      }
    }
    __syncthreads();

    {  // ---------------- layer 1: z = [h0_new | h1] @ [W1;U1] + b1 ----------------
      f32x4 acc[4][4];
#pragma unroll
      for (int q = 0; q < 4; ++q) {
        const f32x4 b = *reinterpret_cast<const f32x4*>(
            &s_b[1][(((wid << 2) + q) << 4) + (lg << 2)]);
#pragma unroll
        for (int rt = 0; rt < 4; ++rt) acc[q][rt] = b;
      }
#pragma unroll
      for (int hf2 = 0; hf2 < 2; ++hf2) {
        const __bf16* src = hf2 ? s_h1[cur] : s_h0[nxt];
#pragma unroll
        for (int kc = 0; kc < 8; ++kc) {
          bf16x8 ib[4];
#pragma unroll
          for (int rt = 0; rt < 4; ++rt) {
            const int r = (rt << 4) + lr;
            const int idx = (r << 8) + (((kc << 5) + (lg << 3)) ^ xr);
            ib[rt] = *reinterpret_cast<const bf16x8*>(&src[idx]);
          }
#pragma unroll
          for (int q = 0; q < 4; ++q) {
            const bf16x8 wf = *reinterpret_cast<const bf16x8*>(
                wp1 + (q * 16 + hf2 * 8 + kc) * 512);
#pragma unroll
            for (int rt = 0; rt < 4; ++rt) acc[q][rt] = MFMA16(wf, ib[rt], acc[q][rt]);
          }
        }
      }
#pragma unroll
      for (int rt = 0; rt < 4; ++rt) {
        const int r = (rt << 4) + lr;
        bf16x4 hv;
        f32x4 cfv;
#pragma unroll
        for (int i = 0; i < 4; ++i) {
          const float cc = fsig(acc[1][rt][i]) * c1s[rt][i] +
                           fsig(acc[0][rt][i]) * ftanh(acc[2][rt][i]);
          c1s[rt][i] = cc;
          const float hh = fsig(acc[3][rt][i]) * ftanh(cc);
          hv[i] = (__bf16)hv[i];  // placeholder overwritten below
          hv[i] = (__bf16)hh;
          cfv[i] = cc;
        }
        *reinterpret_cast<bf16x4*>(&s_h1[nxt][(r << 8) + (e0 ^ xr)]) = hv;
        if (t == 31) {  // c1 final (fp32 accuracy required; small scatter)
          *reinterpret_cast<f32x4*>(out + 73400320 + ((r0 + r) << 8) + e0) = cfv;
        }
      }
    }
    __syncthreads();

    {  // ---- y write: full-cacheline stores (64 lanes x 16B = 1KB contiguous) ----
      // wave wid writes rows 4*wid .. 4*wid+3; one full 1KB row per instruction.
#pragma unroll
      for (int j = 0; j < 4; ++j) {
        const int row = (wid << 2) + j;
        const int xw = (row & 7) << 3;
        const bf16x4 a =
            *reinterpret_cast<const bf16x4*>(&s_h1[nxt][(row << 8) + ((l << 2) ^ xw)]);
        f32x4 v;
#pragma unroll
        for (int i = 0; i < 4; ++i) v[i] = (float)a[i];
        *reinterpret_cast<f32x4*>(out + ((((r0 + row) << 5) + t) << 8) + (l << 2)) = v;
        if (t == 31) {
          // h1 final = y[:,31,:]
          *reinterpret_cast<f32x4*>(out + 71303168 + ((r0 + row) << 8) + (l << 2)) = v;
          // h0 final from s_h0[nxt] (bf16-rounded, |h|<=1 so err <= 2^-10)
          const bf16x4 a0 = *reinterpret_cast<const bf16x4*>(
              &s_h0[nxt][(row << 8) + ((l << 2) ^ xw)]);
          f32x4 v0;
#pragma unroll
          for (int i = 0; i < 4; ++i) v0[i] = (float)a0[i];
          *reinterpret_cast<f32x4*>(out + 67108864 + ((r0 + row) << 8) + (l << 2)) = v0;
        }
      }
      // no barrier needed: next L0 reads/writes only s_h0; next L1's reads of
      // s_h1[nxt] are reads (no writer until L1 epilogue of t+1, behind barriers)
    }
  }
}

extern "C" void kernel_launch(void* const* d_in, const int* in_sizes, int n_in,
                              void* d_out, int out_size, void* d_ws, size_t ws_size,
                              hipStream_t stream) {
  const float* traj = (const float*)d_in[0];
  const float* Wemb = (const float*)d_in[1];
  const float* bemb = (const float*)d_in[2];
  const float* W0 = (const float*)d_in[3];
  const float* U0 = (const float*)d_in[4];
  const float* b0 = (const float*)d_in[5];
  const float* W1 = (const float*)d_in[6];
  const float* U1 = (const float*)d_in[7];
  const float* b1 = (const float*)d_in[8];
  float* out = (float*)d_out;

  __bf16* wb0 = (__bf16*)d_ws;  // 393216 elems = 768 KB
  __bf16* wb1 = wb0 + 393216;   // 524288 elems = 1 MB

  hipLaunchKernelGGL(prep_w0, dim3(1536), dim3(256), 0, stream, W0, U0, wb0);
  hipLaunchKernelGGL(prep_w1, dim3(2048), dim3(256), 0, stream, W1, U1, wb1);
  hipLaunchKernelGGL(lstm_fused, dim3(128), dim3(1024), 0, stream,
                     traj, Wemb, bemb, b0, b1, wb0, wb1, out);
}

// Round 6
// 2852.876 us; speedup vs baseline: 1.1339x; 1.0117x over previous
//
#include <hip/hip_runtime.h>
#include <hip/hip_bf16.h>

// B=8192, T=32, D_IN=2, EMB=128, H=256, 4H=1024
// 128 blocks x 1024 threads (16 waves); block owns 64 batch rows.
// Wave wid owns (w=wid>>2, s=wid&3): cols q*256 + w*64 + s*16 + [0,16), q=0..3 gates.
// MFMA 16x16x32 bf16 swapped operands: D = z^T tile, batch row in lane&15; 4 row-tiles.
// r6: U0 and U1 weight fragments (the recurrent halves, 64 frags = 256 VGPR/lane)
// are PINNED in registers across the whole t-loop; only W0-x (256KB) and W1-h0
// (512KB) stream from L2 each step. Streamed bytes/step/CU: 1.75MB -> 768KB.

typedef __attribute__((ext_vector_type(8))) __bf16 bf16x8;
typedef __attribute__((ext_vector_type(4))) __bf16 bf16x4;
typedef __attribute__((ext_vector_type(4))) float f32x4;

#define MFMA16(a, b, c) __builtin_amdgcn_mfma_f32_16x16x32_bf16(a, b, c, 0, 0, 0)

__device__ __forceinline__ float fexp2(float x) {
#if __has_builtin(__builtin_amdgcn_exp2f)
  return __builtin_amdgcn_exp2f(x);
#else
  return exp2f(x);
#endif
}
__device__ __forceinline__ float frcp(float x) {
#if __has_builtin(__builtin_amdgcn_rcpf)
  return __builtin_amdgcn_rcpf(x);
#else
  return 1.0f / x;
#endif
}
__device__ __forceinline__ float fsig(float x) {
  return frcp(1.0f + fexp2(-1.44269504f * x));
}
__device__ __forceinline__ float ftanh(float x) {
  return 1.0f - 2.0f * frcp(1.0f + fexp2(2.88539008f * x));
}

// ---- weight prep: swizzle [W;U] (K x 1024) fp32 -> per-frag bf16 order ----
__global__ void prep_w0(const float* __restrict__ W0, const float* __restrict__ U0,
                        __bf16* __restrict__ o) {
  const int f = blockIdx.x * 256 + threadIdx.x;  // < 393216
  const int j = f & 7, l5 = (f >> 3) & 63, g = f >> 9;
  const int kc = g % 12, q = (g / 12) & 3, wid = g / 48;
  const int k = (kc << 5) + ((l5 >> 4) << 3) + j;
  const int c = (q << 8) + ((wid >> 2) << 6) + ((wid & 3) << 4) + (l5 & 15);
  const float v = (k < 128) ? W0[(k << 10) + c] : U0[((k - 128) << 10) + c];
  o[f] = (__bf16)v;
}
__global__ void prep_w1(const float* __restrict__ W1, const float* __restrict__ U1,
                        __bf16* __restrict__ o) {
  const int f = blockIdx.x * 256 + threadIdx.x;  // < 524288
  const int j = f & 7, l5 = (f >> 3) & 63, g = f >> 9;
  const int kcx = g & 15, q = (g >> 4) & 3, wid = g >> 6;
  const int k = (kcx << 5) + ((l5 >> 4) << 3) + j;
  const int c = (q << 8) + ((wid >> 2) << 6) + ((wid & 3) << 4) + (l5 & 15);
  const float v = (k < 256) ? W1[(k << 10) + c] : U1[((k - 256) << 10) + c];
  o[f] = (__bf16)v;
}

__global__ __launch_bounds__(1024)
void lstm_fused(const float* __restrict__ traj,
                const float* __restrict__ Wemb,
                const float* __restrict__ bemb,
                const float* __restrict__ bias0,
                const float* __restrict__ bias1,
                const __bf16* __restrict__ wb0,
                const __bf16* __restrict__ wb1,
                float* __restrict__ out) {
  __shared__ float s_We[384];        // We[0][:], We[1][:], be[:]
  __shared__ float s_b[2][1024];     // bias in (ct, cc) order
  __shared__ float s_traj[4096];     // [t][r][d]: t*128 + r*2 + d
  __shared__ __bf16 s_h0[2][16384];  // [buf][r*256 + (e ^ ((r&7)<<3))]
  __shared__ __bf16 s_h1[2][16384];

  const int tid = threadIdx.x;
  const int wid = tid >> 6;
  const int l = tid & 63;
  const int lr = l & 15, lg = l >> 4;
  const int w = wid >> 2, s4 = wid & 3;
  const int xr = (lr & 7) << 3;  // bf16-elem swizzle, fn of row only
  const int r0 = blockIdx.x << 6;

  if (tid < 384) s_We[tid] = (tid < 256) ? Wemb[tid] : bemb[tid - 256];
  {
    const int ct = tid >> 4, cc = tid & 15;
    const int wd = ct >> 2, q = ct & 3;
    const int col = (q << 8) + ((wd >> 2) << 6) + ((wd & 3) << 4) + cc;
    s_b[0][tid] = bias0[col];
    s_b[1][tid] = bias1[col];
  }
  for (int i = tid; i < 4096; i += 1024) {
    const int r = i >> 6, tt = (i >> 1) & 31, d = i & 1;
    s_traj[(tt << 7) + (r << 1) + d] = traj[(r0 << 6) + i];
  }
  for (int i = tid; i < 16384; i += 1024) {
    s_h0[0][i] = (__bf16)0.f;
    s_h1[0][i] = (__bf16)0.f;
  }
  __syncthreads();

  float c0s[4][4] = {};
  float c1s[4][4] = {};
  const __bf16* wp0 = wb0 + wid * 48 * 512 + l * 8;
  const __bf16* wp1 = wb1 + wid * 64 * 512 + l * 8;
  const int e0 = (w << 6) + (s4 << 4) + (lg << 2);

  // ---- pin recurrent weight fragments in registers for the whole t-loop ----
  bf16x8 u0p[4][8];  // U0: L0 kc=4..11
#pragma unroll
  for (int q = 0; q < 4; ++q)
#pragma unroll
    for (int kc = 0; kc < 8; ++kc)
      u0p[q][kc] = *reinterpret_cast<const bf16x8*>(wp0 + (q * 12 + 4 + kc) * 512);
  bf16x8 u1p[4][8];  // U1: L1 hf2=1 kc=0..7
#pragma unroll
  for (int q = 0; q < 4; ++q)
#pragma unroll
    for (int kc = 0; kc < 8; ++kc)
      u1p[q][kc] = *reinterpret_cast<const bf16x8*>(wp1 + (q * 16 + 8 + kc) * 512);

#pragma unroll 1
  for (int t = 0; t < 32; ++t) {
    const int cur = t & 1, nxt = cur ^ 1;

    {  // ---------------- layer 0: z = [x_t | h0] @ [W0;U0] + b0 ----------------
      f32x4 acc[4][4];  // [q][rt]
#pragma unroll
      for (int q = 0; q < 4; ++q) {
        const f32x4 b = *reinterpret_cast<const f32x4*>(
            &s_b[0][(((wid << 2) + q) << 4) + (lg << 2)]);
#pragma unroll
        for (int rt = 0; rt < 4; ++rt) acc[q][rt] = b;
      }
      float t0v[4], t1v[4];
#pragma unroll
      for (int rt = 0; rt < 4; ++rt) {
        const int r = (rt << 4) + lr;
        t0v[rt] = s_traj[(t << 7) + (r << 1)];
        t1v[rt] = s_traj[(t << 7) + (r << 1) + 1];
      }
#pragma unroll
      for (int kc = 0; kc < 4; ++kc) {  // x-part: streamed W0 frags
        bf16x8 ia[4];
#pragma unroll
        for (int rt = 0; rt < 4; ++rt) {
#pragma unroll
          for (int j = 0; j < 8; ++j) {
            const int k = (kc << 5) + (lg << 3) + j;
            const float x =
                fmaf(t0v[rt], s_We[k], fmaf(t1v[rt], s_We[128 + k], s_We[256 + k]));
            ia[rt][j] = (__bf16)fmaxf(x, 0.f);
          }
        }
#pragma unroll
        for (int q = 0; q < 4; ++q) {
          const bf16x8 wf = *reinterpret_cast<const bf16x8*>(wp0 + (q * 12 + kc) * 512);
#pragma unroll
          for (int rt = 0; rt < 4; ++rt) acc[q][rt] = MFMA16(wf, ia[rt], acc[q][rt]);
        }
      }
#pragma unroll
      for (int kc = 0; kc < 8; ++kc) {  // h0-part: PINNED U0 frags
        bf16x8 ia[4];
#pragma unroll
        for (int rt = 0; rt < 4; ++rt) {
          const int r = (rt << 4) + lr;
          const int idx = (r << 8) + (((kc << 5) + (lg << 3)) ^ xr);
          ia[rt] = *reinterpret_cast<const bf16x8*>(&s_h0[cur][idx]);
        }
#pragma unroll
        for (int q = 0; q < 4; ++q) {
#pragma unroll
          for (int rt = 0; rt < 4; ++rt)
            acc[q][rt] = MFMA16(u0p[q][kc], ia[rt], acc[q][rt]);
        }
      }
#pragma unroll
      for (int rt = 0; rt < 4; ++rt) {
        const int r = (rt << 4) + lr;
        bf16x4 hv;
        f32x4 cfv;
#pragma unroll
        for (int i = 0; i < 4; ++i) {
          const float cc = fsig(acc[1][rt][i]) * c0s[rt][i] +
                           fsig(acc[0][rt][i]) * ftanh(acc[2][rt][i]);
          c0s[rt][i] = cc;
          const float hh = fsig(acc[3][rt][i]) * ftanh(cc);
          hv[i] = (__bf16)hh;
          cfv[i] = cc;
        }
        *reinterpret_cast<bf16x4*>(&s_h0[nxt][(r << 8) + (e0 ^ xr)]) = hv;
        if (t == 31) {  // c0 final (fp32 accuracy required; small scatter)
          *reinterpret_cast<f32x4*>(out + 69206016 + ((r0 + r) << 8) + e0) = cfv;
        }
      }
    }
    __syncthreads();

    {  // ---------------- layer 1: z = [h0_new | h1] @ [W1;U1] + b1 ----------------
      f32x4 acc[4][4];
#pragma unroll
      for (int q = 0; q < 4; ++q) {
        const f32x4 b = *reinterpret_cast<const f32x4*>(
            &s_b[1][(((wid << 2) + q) << 4) + (lg << 2)]);
#pragma unroll
        for (int rt = 0; rt < 4; ++rt) acc[q][rt] = b;
      }
#pragma unroll
      for (int kc = 0; kc < 8; ++kc) {  // h0-part: streamed W1 frags
        bf16x8 ib[4];
#pragma unroll
        for (int rt = 0; rt < 4; ++rt) {
          const int r = (rt << 4) + lr;
          const int idx = (r << 8) + (((kc << 5) + (lg << 3)) ^ xr);
          ib[rt] = *reinterpret_cast<const bf16x8*>(&s_h0[nxt][idx]);
        }
#pragma unroll
        for (int q = 0; q < 4; ++q) {
          const bf16x8 wf = *reinterpret_cast<const bf16x8*>(wp1 + (q * 16 + kc) * 512);
#pragma unroll
          for (int rt = 0; rt < 4; ++rt) acc[q][rt] = MFMA16(wf, ib[rt], acc[q][rt]);
        }
      }
#pragma unroll
      for (int kc = 0; kc < 8; ++kc) {  // h1-part: PINNED U1 frags
        bf16x8 ib[4];
#pragma unroll
        for (int rt = 0; rt < 4; ++rt) {
          const int r = (rt << 4) + lr;
          const int idx = (r << 8) + (((kc << 5) + (lg << 3)) ^ xr);
          ib[rt] = *reinterpret_cast<const bf16x8*>(&s_h1[cur][idx]);
        }
#pragma unroll
        for (int q = 0; q < 4; ++q) {
#pragma unroll
          for (int rt = 0; rt < 4; ++rt)
            acc[q][rt] = MFMA16(u1p[q][kc], ib[rt], acc[q][rt]);
        }
      }
#pragma unroll
      for (int rt = 0; rt < 4; ++rt) {
        const int r = (rt << 4) + lr;
        bf16x4 hv;
        f32x4 cfv;
#pragma unroll
        for (int i = 0; i < 4; ++i) {
          const float cc = fsig(acc[1][rt][i]) * c1s[rt][i] +
                           fsig(acc[0][rt][i]) * ftanh(acc[2][rt][i]);
          c1s[rt][i] = cc;
          const float hh = fsig(acc[3][rt][i]) * ftanh(cc);
          hv[i] = (__bf16)hh;
          cfv[i] = cc;
        }
        *reinterpret_cast<bf16x4*>(&s_h1[nxt][(r << 8) + (e0 ^ xr)]) = hv;
        if (t == 31) {  // c1 final (fp32 accuracy required; small scatter)
          *reinterpret_cast<f32x4*>(out + 73400320 + ((r0 + r) << 8) + e0) = cfv;
        }
      }
    }
    __syncthreads();

    {  // ---- y write: full-cacheline stores (64 lanes x 16B = 1KB contiguous) ----
      // wave wid writes rows 4*wid .. 4*wid+3; one full 1KB row per instruction.
#pragma unroll
      for (int j = 0; j < 4; ++j) {
        const int row = (wid << 2) + j;
        const int xw = (row & 7) << 3;
        const bf16x4 a =
            *reinterpret_cast<const bf16x4*>(&s_h1[nxt][(row << 8) + ((l << 2) ^ xw)]);
        f32x4 v;
#pragma unroll
        for (int i = 0; i < 4; ++i) v[i] = (float)a[i];
        *reinterpret_cast<f32x4*>(out + ((((r0 + row) << 5) + t) << 8) + (l << 2)) = v;
        if (t == 31) {
          // h1 final = y[:,31,:]
          *reinterpret_cast<f32x4*>(out + 71303168 + ((r0 + row) << 8) + (l << 2)) = v;
          // h0 final from s_h0[nxt] (bf16-rounded, |h|<=1 so err <= 2^-10)
          const bf16x4 a0 = *reinterpret_cast<const bf16x4*>(
              &s_h0[nxt][(row << 8) + ((l << 2) ^ xw)]);
          f32x4 v0;
#pragma unroll
          for (int i = 0; i < 4; ++i) v0[i] = (float)a0[i];
          *reinterpret_cast<f32x4*>(out + 67108864 + ((r0 + row) << 8) + (l << 2)) = v0;
        }
      }
      // no barrier needed: next L0 reads/writes only s_h0 (behind its own barrier);
      // s_h1[nxt] is not written again until L1 epilogue of t+1, behind barriers.
    }
  }
}

extern "C" void kernel_launch(void* const* d_in, const int* in_sizes, int n_in,
                              void* d_out, int out_size, void* d_ws, size_t ws_size,
                              hipStream_t stream) {
  const float* traj = (const float*)d_in[0];
  const float* Wemb = (const float*)d_in[1];
  const float* bemb = (const float*)d_in[2];
  const float* W0 = (const float*)d_in[3];
  const float* U0 = (const float*)d_in[4];
  const float* b0 = (const float*)d_in[5];
  const float* W1 = (const float*)d_in[6];
  const float* U1 = (const float*)d_in[7];
  const float* b1 = (const float*)d_in[8];
  float* out = (float*)d_out;

  __bf16* wb0 = (__bf16*)d_ws;  // 393216 elems = 768 KB
  __bf16* wb1 = wb0 + 393216;   // 524288 elems = 1 MB

  hipLaunchKernelGGL(prep_w0, dim3(1536), dim3(256), 0, stream, W0, U0, wb0);
  hipLaunchKernelGGL(prep_w1, dim3(2048), dim3(256), 0, stream, W1, U1, wb1);
  hipLaunchKernelGGL(lstm_fused, dim3(128), dim3(1024), 0, stream,
                     traj, Wemb, bemb, b0, b1, wb0, wb1, out);
}

// Round 8
// 2059.505 us; speedup vs baseline: 1.5707x; 1.3852x over previous
//
#include <hip/hip_runtime.h>
#include <hip/hip_bf16.h>

// B=8192, T=32, D_IN=2, EMB=128, H=256, 4H=1024
// 128 blocks x 1024 threads (16 waves); block owns 64 batch rows.
// Wave wid owns cols q*256 + (wid>>2)*64 + (wid&3)*16 + [0,16), q=0..3 gates.
// r8: weights stream through per-wave 4-slot LDS rings via global_load_lds.
// Prefetch depth 3 (slots f+1..f+3 in flight, never the slot being read; the
// victim slot (f-1)&3 was consumed before stage(f+3) issues) -- fixes r7's
// out-of-order-arrival race. Continuous wrap-around staging across timesteps.
// h0/h1 single-buffered; raw s_barrier with lgkmcnt-only waits so the vmcnt
// ring survives barriers.

typedef __attribute__((ext_vector_type(8))) __bf16 bf16x8;
typedef __attribute__((ext_vector_type(4))) __bf16 bf16x4;
typedef __attribute__((ext_vector_type(4))) float f32x4;

#define MFMA16(a, b, c) __builtin_amdgcn_mfma_f32_16x16x32_bf16(a, b, c, 0, 0, 0)

// s_waitcnt imm (gfx9): vmcnt[3:0]|[15:14], expcnt[6:4], lgkm[11:8]
#define WAIT_VM3() __builtin_amdgcn_s_waitcnt(0xF73)     // vmcnt(3), others no-wait
#define WAIT_LGKM0() __builtin_amdgcn_s_waitcnt(0xC07F)  // lgkmcnt(0), others no-wait

__device__ __forceinline__ float fexp2(float x) {
#if __has_builtin(__builtin_amdgcn_exp2f)
  return __builtin_amdgcn_exp2f(x);
#else
  return exp2f(x);
#endif
}
__device__ __forceinline__ float frcp(float x) {
#if __has_builtin(__builtin_amdgcn_rcpf)
  return __builtin_amdgcn_rcpf(x);
#else
  return 1.0f / x;
#endif
}
__device__ __forceinline__ float fsig(float x) {
  return frcp(1.0f + fexp2(-1.44269504f * x));
}
__device__ __forceinline__ float ftanh(float x) {
  return 1.0f - 2.0f * frcp(1.0f + fexp2(2.88539008f * x));
}

// ---- weight prep: swizzle [W;U] (K x 1024) fp32 -> per-frag bf16 order ----
__global__ void prep_w0(const float* __restrict__ W0, const float* __restrict__ U0,
                        __bf16* __restrict__ o) {
  const int f = blockIdx.x * 256 + threadIdx.x;  // < 393216
  const int j = f & 7, l5 = (f >> 3) & 63, g = f >> 9;
  const int kc = g % 12, q = (g / 12) & 3, wid = g / 48;
  const int k = (kc << 5) + ((l5 >> 4) << 3) + j;
  const int c = (q << 8) + ((wid >> 2) << 6) + ((wid & 3) << 4) + (l5 & 15);
  const float v = (k < 128) ? W0[(k << 10) + c] : U0[((k - 128) << 10) + c];
  o[f] = (__bf16)v;
}
__global__ void prep_w1(const float* __restrict__ W1, const float* __restrict__ U1,
                        __bf16* __restrict__ o) {
  const int f = blockIdx.x * 256 + threadIdx.x;  // < 524288
  const int j = f & 7, l5 = (f >> 3) & 63, g = f >> 9;
  const int kcx = g & 15, q = (g >> 4) & 3, wid = g >> 6;
  const int k = (kcx << 5) + ((l5 >> 4) << 3) + j;
  const int c = (q << 8) + ((wid >> 2) << 6) + ((wid & 3) << 4) + (l5 & 15);
  const float v = (k < 256) ? W1[(k << 10) + c] : U1[((k - 256) << 10) + c];
  o[f] = (__bf16)v;
}

__global__ __launch_bounds__(1024)
void lstm_fused(const float* __restrict__ traj,
                const float* __restrict__ Wemb,
                const float* __restrict__ bemb,
                const float* __restrict__ bias0,
                const float* __restrict__ bias1,
                const __bf16* __restrict__ wb0,
                const __bf16* __restrict__ wb1,
                float* __restrict__ out) {
  __shared__ float s_We[384];       // We[0][:], We[1][:], be[:]
  __shared__ float s_b[2][1024];    // bias in (ct, cc) order
  __shared__ float s_traj[4096];    // [t][r][d]
  __shared__ __bf16 s_h0[16384];    // single buf: [r*256 + (e ^ ((r&7)<<3))]
  __shared__ __bf16 s_h1[16384];
  __shared__ __bf16 s_ring[32768];  // 16 waves x 4 slots x 512 elems (1KB)

  const int tid = threadIdx.x;
  const int wid = tid >> 6;
  const int l = tid & 63;
  const int lr = l & 15, lg = l >> 4;
  const int w = wid >> 2, s4 = wid & 3;
  const int xr = (lr & 7) << 3;
  const int r0 = blockIdx.x << 6;

  if (tid < 384) s_We[tid] = (tid < 256) ? Wemb[tid] : bemb[tid - 256];
  {
    const int ct = tid >> 4, cc = tid & 15;
    const int wd = ct >> 2, q = ct & 3;
    const int col = (q << 8) + ((wd >> 2) << 6) + ((wd & 3) << 4) + cc;
    s_b[0][tid] = bias0[col];
    s_b[1][tid] = bias1[col];
  }
  for (int i = tid; i < 4096; i += 1024) {
    const int r = i >> 6, tt = (i >> 1) & 31, d = i & 1;
    s_traj[(tt << 7) + (r << 1) + d] = traj[(r0 << 6) + i];
  }
  for (int i = tid; i < 16384; i += 1024) {
    s_h0[i] = (__bf16)0.f;
    s_h1[i] = (__bf16)0.f;
  }
  __syncthreads();

  float c0s[4][4] = {};
  float c1s[4][4] = {};
  const __bf16* wp0 = wb0 + wid * 48 * 512 + l * 8;
  const __bf16* wp1 = wb1 + wid * 64 * 512 + l * 8;
  const int e0 = (w << 6) + (s4 << 4) + (lg << 2);
  __bf16* ringp = &s_ring[wid << 11];  // 4 slots x 512 elems per wave

  // stage frag fi (0..111) into ring slot fi&3 via global_load_lds (16B/lane)
  auto stage = [&](int fi) {
    const __bf16* src = (fi < 48)
        ? wp0 + (((fi & 3) * 12 + (fi >> 2)) << 9)
        : wp1 + ((((fi - 48) & 3) * 16 + ((fi - 48) >> 2)) << 9);
    __builtin_amdgcn_global_load_lds(
        (const __attribute__((address_space(1))) void*)src,
        (__attribute__((address_space(3))) void*)(ringp + ((fi & 3) << 9)),
        16, 0, 0);
  };
  auto ring_read = [&](int fi) {
    return *reinterpret_cast<const bf16x8*>(ringp + ((fi & 3) << 9) + (l << 3));
  };

#define RAW_BARRIER()                \
  WAIT_LGKM0();                      \
  __builtin_amdgcn_sched_barrier(0); \
  __builtin_amdgcn_s_barrier()

  // prime the ring 3 deep
  stage(0); stage(1); stage(2);

#pragma unroll 1
  for (int t = 0; t < 32; ++t) {
    {  // ---------------- layer 0: z = [x_t | h0] @ [W0;U0] + b0 ----------------
      f32x4 acc[4][4];  // [q][rt]
#pragma unroll
      for (int q = 0; q < 4; ++q) {
        const f32x4 b = *reinterpret_cast<const f32x4*>(
            &s_b[0][(((wid << 2) + q) << 4) + (lg << 2)]);
#pragma unroll
        for (int rt = 0; rt < 4; ++rt) acc[q][rt] = b;
      }
      float t0v[4], t1v[4];
#pragma unroll
      for (int rt = 0; rt < 4; ++rt) {
        const int r = (rt << 4) + lr;
        t0v[rt] = s_traj[(t << 7) + (r << 1)];
        t1v[rt] = s_traj[(t << 7) + (r << 1) + 1];
      }
#pragma unroll
      for (int kc = 0; kc < 12; ++kc) {
        bf16x8 ia[4];
        if (kc < 4) {  // x-part computed on the fly
#pragma unroll
          for (int rt = 0; rt < 4; ++rt) {
#pragma unroll
            for (int j = 0; j < 8; ++j) {
              const int k = (kc << 5) + (lg << 3) + j;
              const float x = fmaf(t0v[rt], s_We[k],
                                   fmaf(t1v[rt], s_We[128 + k], s_We[256 + k]));
              ia[rt][j] = (__bf16)fmaxf(x, 0.f);
            }
          }
        } else {  // h0 part from LDS
#pragma unroll
          for (int rt = 0; rt < 4; ++rt) {
            const int r = (rt << 4) + lr;
            ia[rt] = *reinterpret_cast<const bf16x8*>(
                &s_h0[(r << 8) + ((((kc - 4) << 5) + (lg << 3)) ^ xr)]);
          }
        }
#pragma unroll
        for (int q = 0; q < 4; ++q) {
          const int f = (kc << 2) + q;
          stage((f + 3) % 112);  // wraps into next step's frags at the tail
          WAIT_VM3();
          __builtin_amdgcn_sched_barrier(0);
          const bf16x8 wf = ring_read(f);
#pragma unroll
          for (int rt = 0; rt < 4; ++rt) acc[q][rt] = MFMA16(wf, ia[rt], acc[q][rt]);
        }
      }
      RAW_BARRIER();  // all s_h0 reads done -> safe to overwrite in place
#pragma unroll
      for (int rt = 0; rt < 4; ++rt) {
        const int r = (rt << 4) + lr;
        bf16x4 hv;
        f32x4 cfv;
#pragma unroll
        for (int i = 0; i < 4; ++i) {
          const float cc = fsig(acc[1][rt][i]) * c0s[rt][i] +
                           fsig(acc[0][rt][i]) * ftanh(acc[2][rt][i]);
          c0s[rt][i] = cc;
          const float hh = fsig(acc[3][rt][i]) * ftanh(cc);
          hv[i] = (__bf16)hh;
          cfv[i] = cc;
        }
        *reinterpret_cast<bf16x4*>(&s_h0[(r << 8) + (e0 ^ xr)]) = hv;
        if (t == 31) {  // c0 final
          *reinterpret_cast<f32x4*>(out + 69206016 + ((r0 + r) << 8) + e0) = cfv;
        }
      }
      RAW_BARRIER();  // h0(t) complete in LDS
    }

    {  // ---------------- layer 1: z = [h0_new | h1] @ [W1;U1] + b1 ----------------
      f32x4 acc[4][4];
#pragma unroll
      for (int q = 0; q < 4; ++q) {
        const f32x4 b = *reinterpret_cast<const f32x4*>(
            &s_b[1][(((wid << 2) + q) << 4) + (lg << 2)]);
#pragma unroll
        for (int rt = 0; rt < 4; ++rt) acc[q][rt] = b;
      }
#pragma unroll
      for (int kc8 = 0; kc8 < 16; ++kc8) {
        bf16x8 ib[4];
        const __bf16* src = (kc8 < 8) ? s_h0 : s_h1;
        const int kcl = kc8 & 7;
#pragma unroll
        for (int rt = 0; rt < 4; ++rt) {
          const int r = (rt << 4) + lr;
          ib[rt] = *reinterpret_cast<const bf16x8*>(
              &src[(r << 8) + (((kcl << 5) + (lg << 3)) ^ xr)]);
        }
#pragma unroll
        for (int q = 0; q < 4; ++q) {
          const int f = 48 + (kc8 << 2) + q;
          stage((f + 3) % 112);
          WAIT_VM3();
          __builtin_amdgcn_sched_barrier(0);
          const bf16x8 wf = ring_read(f);
#pragma unroll
          for (int rt = 0; rt < 4; ++rt) acc[q][rt] = MFMA16(wf, ib[rt], acc[q][rt]);
        }
      }
      RAW_BARRIER();  // all s_h1 reads done -> safe to overwrite in place
#pragma unroll
      for (int rt = 0; rt < 4; ++rt) {
        const int r = (rt << 4) + lr;
        bf16x4 hv;
        f32x4 cfv;
#pragma unroll
        for (int i = 0; i < 4; ++i) {
          const float cc = fsig(acc[1][rt][i]) * c1s[rt][i] +
                           fsig(acc[0][rt][i]) * ftanh(acc[2][rt][i]);
          c1s[rt][i] = cc;
          const float hh = fsig(acc[3][rt][i]) * ftanh(cc);
          hv[i] = (__bf16)hh;
          cfv[i] = cc;
        }
        *reinterpret_cast<bf16x4*>(&s_h1[(r << 8) + (e0 ^ xr)]) = hv;
        if (t == 31) {  // c1 final
          *reinterpret_cast<f32x4*>(out + 73400320 + ((r0 + r) << 8) + e0) = cfv;
        }
      }
      RAW_BARRIER();  // h1(t) complete in LDS
    }

    {  // ---- y write: full-cacheline stores (64 lanes x 16B = 1KB per row) ----
#pragma unroll
      for (int j = 0; j < 4; ++j) {
        const int row = (wid << 2) + j;
        const int xw = (row & 7) << 3;
        const bf16x4 a =
            *reinterpret_cast<const bf16x4*>(&s_h1[(row << 8) + ((l << 2) ^ xw)]);
        f32x4 v;
#pragma unroll
        for (int i = 0; i < 4; ++i) v[i] = (float)a[i];
        *reinterpret_cast<f32x4*>(out + ((((r0 + row) << 5) + t) << 8) + (l << 2)) = v;
        if (t == 31) {
          *reinterpret_cast<f32x4*>(out + 71303168 + ((r0 + row) << 8) + (l << 2)) = v;
          const bf16x4 a0 = *reinterpret_cast<const bf16x4*>(
              &s_h0[(row << 8) + ((l << 2) ^ xw)]);
          f32x4 v0;
#pragma unroll
          for (int i = 0; i < 4; ++i) v0[i] = (float)a0[i];
          *reinterpret_cast<f32x4*>(out + 67108864 + ((r0 + row) << 8) + (l << 2)) = v0;
        }
      }
      // stores sit in the vmcnt queue ahead of the next stages; the next
      // WAIT_VM3 conservatively drains them (small boundary bubble, correct).
    }
  }
}

extern "C" void kernel_launch(void* const* d_in, const int* in_sizes, int n_in,
                              void* d_out, int out_size, void* d_ws, size_t ws_size,
                              hipStream_t stream) {
  const float* traj = (const float*)d_in[0];
  const float* Wemb = (const float*)d_in[1];
  const float* bemb = (const float*)d_in[2];
  const float* W0 = (const float*)d_in[3];
  const float* U0 = (const float*)d_in[4];
  const float* b0 = (const float*)d_in[5];
  const float* W1 = (const float*)d_in[6];
  const float* U1 = (const float*)d_in[7];
  const float* b1 = (const float*)d_in[8];
  float* out = (float*)d_out;

  __bf16* wb0 = (__bf16*)d_ws;  // 393216 elems = 768 KB
  __bf16* wb1 = wb0 + 393216;   // 524288 elems = 1 MB

  hipLaunchKernelGGL(prep_w0, dim3(1536), dim3(256), 0, stream, W0, U0, wb0);
  hipLaunchKernelGGL(prep_w1, dim3(2048), dim3(256), 0, stream, W1, U1, wb1);
  hipLaunchKernelGGL(lstm_fused, dim3(128), dim3(1024), 0, stream,
                     traj, Wemb, bemb, b0, b1, wb0, wb1, out);
}